// Round 7
// baseline (110.989 us; speedup 1.0000x reference)
//
#include <hip/hip_runtime.h>

// RBF: out[b,l] = exp(-(1/256) * max(||x_b||^2 + ||l_l||^2 - 2 x_b·l_l, 0))
// B=8192, L=2048, D=256. bf16 MFMA GEMM + fused epilogue.
// R2: XOR-swizzled LDS (kept for B). R3: swapped MFMA -> f32x4 NT stores (kept).
// R5/R6: REVERTED (256^2 structures lose cross-block overlap at 1 blk/CU).
// R7: back to 128^2 / 4 waves / BK=64 dbuf, but A fragments read DIRECTLY
//     from global (flatmm-style): LDS 64->32 KB (B only) => 3 blocks/CU
//     (was 2), staging halves, A-loads bypass barriers (reg-dep waits).
//     Bijective XCD swizzle: each XCD owns 8 bm-panels (512 KB A + 1 MB B
//     L2-resident, so A's 16x re-read is own-L2). NT output stores.

typedef __bf16 bf16x8 __attribute__((ext_vector_type(8)));
typedef float  f32x4  __attribute__((ext_vector_type(4)));

#define B_ROWS 8192
#define L_ROWS 2048
#define K_DIM  256

#define GLD_LDS(g, l) __builtin_amdgcn_global_load_lds(                      \
    (const __attribute__((address_space(1))) void*)(g),                      \
    (__attribute__((address_space(3))) void*)(l), 16, 0, 0)

__device__ __forceinline__ unsigned short f32_to_bf16_rne(float f) {
    union { float f; unsigned int u; } v; v.f = f;
    unsigned int u = v.u;
    unsigned int r = (u + 0x7fffu + ((u >> 16) & 1u)) >> 16;
    return (unsigned short)r;
}

// One wave per 256-float row: convert to bf16 (RNE) + fp32 squared-norm.
__global__ __launch_bounds__(256) void cvt_rows_kernel(
    const float* __restrict__ x, const float* __restrict__ lm,
    unsigned short* __restrict__ xb, unsigned short* __restrict__ lb,
    float* __restrict__ x2, float* __restrict__ l2)
{
    const int lane = threadIdx.x & 63;
    const int gw   = blockIdx.x * 4 + (threadIdx.x >> 6);
    const float* in; unsigned short* outb; float* sq; int row;
    if (gw < B_ROWS) { in = x;  outb = xb; sq = x2; row = gw; }
    else             { in = lm; outb = lb; sq = l2; row = gw - B_ROWS; }
    const float4 v = ((const float4*)(in + (size_t)row * K_DIM))[lane];
    ushort4 o;
    o.x = f32_to_bf16_rne(v.x);
    o.y = f32_to_bf16_rne(v.y);
    o.z = f32_to_bf16_rne(v.z);
    o.w = f32_to_bf16_rne(v.w);
    ((ushort4*)(outb + (size_t)row * K_DIM))[lane] = o;
    float s = v.x*v.x + v.y*v.y + v.z*v.z + v.w*v.w;
    #pragma unroll
    for (int off = 32; off > 0; off >>= 1) s += __shfl_down(s, off, 64);
    if (lane == 0) sq[row] = s;
}

// 128x128 tile GEMM, NT layout. 4 waves 2x2; wave tile 64x64 = 4x4 frags of
// 16x16x32 bf16 MFMA. BK=64. B double-buffered in LDS (2 x 16 KB), XOR-swizzled
// (granule g at row R stored at g ^ (R&7); linear gld_lds dest + pre-swizzled
// global source, rule #21). A fragments loaded straight from global to VGPR.
__global__ __launch_bounds__(256) void rbf_gemm_kernel(
    const unsigned short* __restrict__ A,   // bf16 bits [8192][256]
    const unsigned short* __restrict__ Bm,  // bf16 bits [2048][256]
    const float* __restrict__ x2,
    const float* __restrict__ l2,
    float* __restrict__ out)                // [8192][2048]
{
    __shared__ unsigned short Bs[2][128 * 64];  // 2 x 16 KB = 32 KB total

    const int tid  = threadIdx.x;
    const int wave = tid >> 6;
    const int lane = tid & 63;
    const int wm = wave >> 1, wn = wave & 1;

    // Bijective XCD swizzle (1024 blocks, 1024%8==0): XCD x gets bm-panel
    // chunk [x*8, x*8+8) across all 16 bn -> per-XCD L2 working set =
    // 512 KB A + 1 MB B, fully resident.
    const int bid = blockIdx.x;
    const int xcd = bid & 7;
    const int idx = bid >> 3;            // 0..127
    const int bm  = xcd * 8 + (idx & 7); // 0..63
    const int bn  = idx >> 3;            // 0..15

    f32x4 acc[4][4];
    #pragma unroll
    for (int i = 0; i < 4; ++i)
        #pragma unroll
        for (int j = 0; j < 4; ++j)
            acc[i][j] = (f32x4){0.f, 0.f, 0.f, 0.f};

    // B staging: lane l -> LDS base + 16*l == row l>>3 of its 8-row group,
    // granule l&7; swizzled source granule = (l&7) ^ (l>>3).
    const int ldrow = lane >> 3;
    const int ldcol = (((lane & 7) ^ ldrow) * 8);

    const unsigned short* Bb = Bm + (size_t)(bn * 128) * K_DIM;
    // Per-lane A base: row = bm*128 + wm*64 + (lane&15), k-quad = (lane>>4)*8.
    const unsigned short* Ap = A + (size_t)(bm * 128 + wm * 64 + (lane & 15)) * K_DIM
                                 + (lane >> 4) * 8;

    // 4 global_load_lds per wave per stage (B tile 128 rows x 64 cols).
#define STAGE_B(buf, k0)                                                     \
    _Pragma("unroll")                                                        \
    for (int it = 0; it < 4; ++it) {                                         \
        const int r = wave * 32 + it * 8;                                    \
        GLD_LDS(Bb + (r + ldrow) * K_DIM + (k0) + ldcol, &Bs[buf][r * 64]);  \
    }

    STAGE_B(0, 0);

    const int xr = (lane & 7) << 4;    // read-side XOR (bytes) == (row&7)<<4

    #pragma unroll
    for (int t = 0; t < 4; ++t) {       // K_DIM/64 = 4 K-steps
        const int cur = t & 1;
        const int k0 = t * 64;

        // A fragments for THIS tile: 8 x b128 gathers (L2-resident panel).
        bf16x8 af[4][2];
        #pragma unroll
        for (int mt = 0; mt < 4; ++mt) {
            af[mt][0] = *(const bf16x8*)&Ap[(size_t)mt * 16 * K_DIM + k0];
            af[mt][1] = *(const bf16x8*)&Ap[(size_t)mt * 16 * K_DIM + k0 + 32];
        }
        if (t < 3) { STAGE_B(cur ^ 1, k0 + 64); }
        // Counted wait: leave only next-tile B (4 newest) in flight; this
        // tile's B writes (and A reg-loads, older) are complete. The
        // compiler additionally tracks af register deps on its own.
        if (t < 3) asm volatile("s_waitcnt vmcnt(4)" ::: "memory");
        else       asm volatile("s_waitcnt vmcnt(0)" ::: "memory");
        asm volatile("s_barrier" ::: "memory");   // publish Bs[cur]

        #pragma unroll
        for (int kk = 0; kk < 64; kk += 32) {
            const int osw = ((kk * 2 + (lane >> 4) * 16) ^ xr) >> 1;  // elems
            bf16x8 bfr[4];
            #pragma unroll
            for (int nt = 0; nt < 4; ++nt)
                bfr[nt] = *(const bf16x8*)&Bs[cur][(wn*64 + nt*16 + (lane & 15)) * 64 + osw];
            // Swapped operands: per-lane row-major D (m=lane&15,
            // n=(lane>>4)*4+reg) -> f32x4 stores in epilogue.
            #pragma unroll
            for (int mt = 0; mt < 4; ++mt)
                #pragma unroll
                for (int nt = 0; nt < 4; ++nt)
                    acc[mt][nt] = __builtin_amdgcn_mfma_f32_16x16x32_bf16(
                        bfr[nt], af[mt][kk >> 5], acc[mt][nt], 0, 0, 0);
        }
        // Protect Bs[cur] before t+1's STAGE_B overwrites it.
        if (t < 3) asm volatile("s_barrier" ::: "memory");
    }
#undef STAGE_B

    // Epilogue (transposed D): row = ...+(lane&15) fixed per mt,
    // cols = ...+(lane>>4)*4 + {0..3} consecutive -> dwordx4 NT stores.
    const float gamma = 1.0f / 256.0f;
    const int row0 = bm * 128 + wm * 64 + (lane & 15);
    const int col0 = bn * 128 + wn * 64 + (lane >> 4) * 4;

    f32x4 lv[4];
    #pragma unroll
    for (int nt = 0; nt < 4; ++nt) lv[nt] = *(const f32x4*)&l2[col0 + nt * 16];

    #pragma unroll
    for (int mt = 0; mt < 4; ++mt) {
        const int row = row0 + mt * 16;
        const float xv = x2[row];
        const size_t rb = (size_t)row * L_ROWS;
        #pragma unroll
        for (int nt = 0; nt < 4; ++nt) {
            f32x4 v;
            #pragma unroll
            for (int r = 0; r < 4; ++r) {
                float d2 = fmaxf(xv + lv[nt][r] - 2.0f * acc[mt][nt][r], 0.0f);
                v[r] = __expf(-gamma * d2);
            }
            __builtin_nontemporal_store(v, (f32x4*)&out[rb + col0 + nt * 16]);
        }
    }
}

extern "C" void kernel_launch(void* const* d_in, const int* in_sizes, int n_in,
                              void* d_out, int out_size, void* d_ws, size_t ws_size,
                              hipStream_t stream) {
    const float* x  = (const float*)d_in[0];   // [8192, 256]
    const float* lm = (const float*)d_in[1];   // [2048, 256]
    float* out = (float*)d_out;

    char* ws = (char*)d_ws;
    unsigned short* xb = (unsigned short*)ws;                               // 4 MB
    unsigned short* lb = (unsigned short*)(ws + (size_t)B_ROWS*K_DIM*2);    // 1 MB
    float* x2 = (float*)(ws + (size_t)B_ROWS*K_DIM*2 + (size_t)L_ROWS*K_DIM*2);
    float* l2 = x2 + B_ROWS;

    cvt_rows_kernel<<<(B_ROWS + L_ROWS)/4, 256, 0, stream>>>(x, lm, xb, lb, x2, l2);
    rbf_gemm_kernel<<<1024, 256, 0, stream>>>(xb, lb, x2, l2, out);
}

// Round 8
// 90.610 us; speedup vs baseline: 1.2249x; 1.2249x over previous
//
#include <hip/hip_runtime.h>

// RBF: out[b,l] = exp(-(1/256) * max(||x_b||^2 + ||l_l||^2 - 2 x_b·l_l, 0))
// B=8192, L=2048, D=256. bf16 MFMA GEMM + fused epilogue.
// FINAL (R8 = R2 verbatim, the measured best at 90.6 us):
//   R1: double-buffered LDS + counted vmcnt(8) pipeline.
//   R2: T2 XOR-swizzle on LDS tiles (both-sides involution, rule #21).
// Post-R2 structural variants all regressed: 256^2 2-phase (+7.7),
// 256^2 8-phase (+9.7), BK=32@4blk (+16, spills), A-from-global (+20);
// store-vectorization was noise. Remaining time = harness resets (~58 us)
// + kernels near pipe-sum floor.

typedef __bf16 bf16x8 __attribute__((ext_vector_type(8)));
typedef float  f32x4  __attribute__((ext_vector_type(4)));

#define B_ROWS 8192
#define L_ROWS 2048
#define K_DIM  256

#define GLD_LDS(g, l) __builtin_amdgcn_global_load_lds(                      \
    (const __attribute__((address_space(1))) void*)(g),                      \
    (__attribute__((address_space(3))) void*)(l), 16, 0, 0)

__device__ __forceinline__ unsigned short f32_to_bf16_rne(float f) {
    union { float f; unsigned int u; } v; v.f = f;
    unsigned int u = v.u;
    unsigned int r = (u + 0x7fffu + ((u >> 16) & 1u)) >> 16;
    return (unsigned short)r;
}

// One wave per 256-float row: convert to bf16 (RNE) + fp32 squared-norm.
// Fused: first B_ROWS waves handle x, remaining L_ROWS waves handle landmarks.
__global__ __launch_bounds__(256) void cvt_rows_kernel(
    const float* __restrict__ x, const float* __restrict__ lm,
    unsigned short* __restrict__ xb, unsigned short* __restrict__ lb,
    float* __restrict__ x2, float* __restrict__ l2)
{
    const int lane = threadIdx.x & 63;
    const int gw   = blockIdx.x * 4 + (threadIdx.x >> 6);
    const float* in; unsigned short* outb; float* sq; int row;
    if (gw < B_ROWS) { in = x;  outb = xb; sq = x2; row = gw; }           // wave-uniform branch
    else             { in = lm; outb = lb; sq = l2; row = gw - B_ROWS; }
    const float4 v = ((const float4*)(in + (size_t)row * K_DIM))[lane];
    ushort4 o;
    o.x = f32_to_bf16_rne(v.x);
    o.y = f32_to_bf16_rne(v.y);
    o.z = f32_to_bf16_rne(v.z);
    o.w = f32_to_bf16_rne(v.w);
    ((ushort4*)(outb + (size_t)row * K_DIM))[lane] = o;
    float s = v.x*v.x + v.y*v.y + v.z*v.z + v.w*v.w;
    #pragma unroll
    for (int off = 32; off > 0; off >>= 1) s += __shfl_down(s, off, 64);
    if (lane == 0) sq[row] = s;
}

// 128x128 tile GEMM, NT layout (A [M,K] row-major, B [N,K] row-major),
// 4 waves in 2x2, each wave 64x64 via 4x4 of 16x16x32 bf16 MFMA. BK=64.
// Double-buffered LDS; next K-tile staged before compute; counted vmcnt.
// LDS layout: XOR-swizzled — LDS[row R][granule g] = global[R][g ^ (R&7)],
// granule = 16 B (8 bf16). Staging realizes this by pre-swizzling the
// per-lane global source (dest stays linear, HW rule); reads XOR the
// within-row byte offset with (R&7)<<4. R&7 == lane-derived on both sides.
__global__ __launch_bounds__(256) void rbf_gemm_kernel(
    const unsigned short* __restrict__ A,   // bf16 bits [8192][256]
    const unsigned short* __restrict__ Bm,  // bf16 bits [2048][256]
    const float* __restrict__ x2,
    const float* __restrict__ l2,
    float* __restrict__ out)                // [8192][2048]
{
    __shared__ unsigned short As[2][128 * 64];  // 2 x 16 KB
    __shared__ unsigned short Bs[2][128 * 64];  // 2 x 16 KB

    const int tid  = threadIdx.x;
    const int wave = tid >> 6;
    const int lane = tid & 63;
    const int wm = wave >> 1, wn = wave & 1;
    const int bm = blockIdx.x, bn = blockIdx.y;

    f32x4 acc[4][4];
    #pragma unroll
    for (int i = 0; i < 4; ++i)
        #pragma unroll
        for (int j = 0; j < 4; ++j)
            acc[i][j] = (f32x4){0.f, 0.f, 0.f, 0.f};

    // Staging: per wave-load, lane l writes LDS base + l*16 bytes (HW rule)
    // == row (l>>3) of the 8-row group, granule (l&7). Source granule is
    // XOR'd with the row-within-group (l>>3) == (R&7) since row groups are
    // 8-aligned. This realizes the swizzled layout with a linear dest.
    const int ldrow = lane >> 3;                         // 0..7 rows per wave-load
    const int ldcol = (((lane & 7) ^ ldrow) * 8);        // swizzled source granule

    const unsigned short* Ab = A  + (size_t)(bm * 128) * K_DIM;
    const unsigned short* Bb = Bm + (size_t)(bn * 128) * K_DIM;

    // 8 global_load_lds per wave per stage (4 it x 2 arrays).
#define STAGE(buf, k0)                                                       \
    _Pragma("unroll")                                                        \
    for (int it = 0; it < 4; ++it) {                                         \
        const int r = wave * 32 + it * 8;                                    \
        GLD_LDS(Ab + (r + ldrow) * K_DIM + (k0) + ldcol, &As[buf][r * 64]);  \
        GLD_LDS(Bb + (r + ldrow) * K_DIM + (k0) + ldcol, &Bs[buf][r * 64]);  \
    }

    STAGE(0, 0);

    const int xr = (lane & 7) << 4;    // read-side XOR (bytes) == (R&7)<<4

    #pragma unroll
    for (int t = 0; t < 4; ++t) {       // K_DIM/64 = 4 K-steps
        const int cur = t & 1;
        if (t < 3) { STAGE(cur ^ 1, (t + 1) * 64); }
        // Counted wait: the 8 newest (next-tile) loads may stay in flight;
        // everything older (this tile's 8) is complete. Never vmcnt(0) mid-loop.
        if (t < 3) asm volatile("s_waitcnt vmcnt(8)" ::: "memory");
        else       asm volatile("s_waitcnt vmcnt(0)" ::: "memory");
        asm volatile("s_barrier" ::: "memory");   // all waves' stage(t) done

        #pragma unroll
        for (int kk = 0; kk < 64; kk += 32) {
            // Within-row byte offset before swizzle: kk*2 + quad*16.
            const int osw = ((kk * 2 + (lane >> 4) * 16) ^ xr) >> 1;  // elems
            bf16x8 af[4], bfr[4];
            #pragma unroll
            for (int tt = 0; tt < 4; ++tt) {
                af[tt]  = *(const bf16x8*)&As[cur][(wm*64 + tt*16 + (lane & 15)) * 64 + osw];
                bfr[tt] = *(const bf16x8*)&Bs[cur][(wn*64 + tt*16 + (lane & 15)) * 64 + osw];
            }
            #pragma unroll
            for (int mt = 0; mt < 4; ++mt)
                #pragma unroll
                for (int nt = 0; nt < 4; ++nt)
                    acc[mt][nt] = __builtin_amdgcn_mfma_f32_16x16x32_bf16(
                        af[mt], bfr[nt], acc[mt][nt], 0, 0, 0);
        }
        // Protect buf[cur] from being overwritten by t+1's STAGE (which
        // targets buf[(t+2)&1] == buf[cur]).
        if (t < 3) asm volatile("s_barrier" ::: "memory");
    }
#undef STAGE

    // Epilogue: C/D layout col=lane&15, row=(lane>>4)*4+reg (m89-verified).
    const float gamma = 1.0f / 256.0f;
    const int col0 = bn * 128 + wn * 64 + (lane & 15);
    const int row0 = bm * 128 + wm * 64 + (lane >> 4) * 4;
    #pragma unroll
    for (int mt = 0; mt < 4; ++mt) {
        const int rb = row0 + mt * 16;
        float xv[4];
        #pragma unroll
        for (int r = 0; r < 4; ++r) xv[r] = x2[rb + r];
        #pragma unroll
        for (int nt = 0; nt < 4; ++nt) {
            const int c  = col0 + nt * 16;
            const float lv = l2[c];
            #pragma unroll
            for (int r = 0; r < 4; ++r) {
                float d2 = fmaxf(xv[r] + lv - 2.0f * acc[mt][nt][r], 0.0f);
                out[(size_t)(rb + r) * L_ROWS + c] = __expf(-gamma * d2);
            }
        }
    }
}

extern "C" void kernel_launch(void* const* d_in, const int* in_sizes, int n_in,
                              void* d_out, int out_size, void* d_ws, size_t ws_size,
                              hipStream_t stream) {
    const float* x  = (const float*)d_in[0];   // [8192, 256]
    const float* lm = (const float*)d_in[1];   // [2048, 256]
    float* out = (float*)d_out;

    char* ws = (char*)d_ws;
    unsigned short* xb = (unsigned short*)ws;                               // 4 MB
    unsigned short* lb = (unsigned short*)(ws + (size_t)B_ROWS*K_DIM*2);    // 1 MB
    float* x2 = (float*)(ws + (size_t)B_ROWS*K_DIM*2 + (size_t)L_ROWS*K_DIM*2);
    float* l2 = x2 + B_ROWS;

    cvt_rows_kernel<<<(B_ROWS + L_ROWS)/4, 256, 0, stream>>>(x, lm, xb, lb, x2, l2);
    rbf_gemm_kernel<<<dim3(B_ROWS/128, L_ROWS/128), 256, 0, stream>>>(xb, lb, x2, l2, out);
}